// Round 1
// baseline (93.935 us; speedup 1.0000x reference)
//
#include <hip/hip_runtime.h>
#include <hip/hip_bf16.h>
#include <math.h>

#define B_DIM 4096
#define CIN   2048
#define COUT  2048

typedef _Float16 f16x8 __attribute__((ext_vector_type(8)));
typedef _Float16 f16x4 __attribute__((ext_vector_type(4)));
typedef float    f32x4 __attribute__((ext_vector_type(4)));

// ---------------------------------------------------------------- reductions
__device__ inline float wave_reduce_sum(float v) {
#pragma unroll
    for (int off = 32; off > 0; off >>= 1)
        v += __shfl_down(v, off, 64);
    return v;
}

// ---------------------------------------------------------------- K1: max|W|
__global__ void maxabs_kernel(const float* __restrict__ w,
                              unsigned int* __restrict__ out) {
    const size_t n4 = (size_t)COUT * CIN / 4;
    const f32x4* w4 = (const f32x4*)w;
    float m = 0.f;
    for (size_t i = (size_t)blockIdx.x * blockDim.x + threadIdx.x; i < n4;
         i += (size_t)gridDim.x * blockDim.x) {
        f32x4 v = w4[i];
        m = fmaxf(m, fmaxf(fmaxf(fabsf(v[0]), fabsf(v[1])),
                           fmaxf(fabsf(v[2]), fabsf(v[3]))));
    }
#pragma unroll
    for (int off = 32; off > 0; off >>= 1)
        m = fmaxf(m, __shfl_down(m, off, 64));
    __shared__ float red[4];
    if ((threadIdx.x & 63) == 0) red[threadIdx.x >> 6] = m;
    __syncthreads();
    if (threadIdx.x == 0) {
        m = fmaxf(fmaxf(red[0], red[1]), fmaxf(red[2], red[3]));
        atomicMax(out, __float_as_uint(m));  // all values >= 0: uint order == float order
    }
}

// ------------------------------------------------- K2: wq -> V(fp16), term_w
__global__ void prep_w_kernel(const float* __restrict__ weight,
                              const float* __restrict__ phases,
                              const float* __restrict__ disks,
                              const unsigned int* __restrict__ maxbuf,
                              _Float16* __restrict__ V,
                              float* __restrict__ term_w) {
    const int o = blockIdx.x;
    const float maxw = tanhf(__uint_as_float(maxbuf[0]));  // max|tanh(W)| = tanh(max|W|)
    const float two_m = 2.0f * maxw;
    float sum = 0.f;
    for (int i = threadIdx.x; i < CIN; i += 256) {
        float w  = tanhf(weight[(size_t)o * CIN + i]);
        float wq = rintf((w / two_m + 0.5f) * 255.f) / 255.f;
        float d0 = disks[2 * i], d1 = disks[2 * i + 1];
        float s  = sinf(phases[i]) * (d0 + d1);
        V[(size_t)o * CIN + i] = (_Float16)(wq * s);
        sum += wq * wq * (d0 - d1);
    }
    sum = wave_reduce_sum(sum);
    __shared__ float red[4];
    if ((threadIdx.x & 63) == 0) red[threadIdx.x >> 6] = sum;
    __syncthreads();
    if (threadIdx.x == 0)
        term_w[o] = 0.25f * (red[0] + red[1] + red[2] + red[3]);
}

// ------------------------------------------------- K3: xq -> XQ(fp16), term_x
__global__ void prep_x_kernel(const float* __restrict__ x,
                              const float* __restrict__ disks,
                              _Float16* __restrict__ XQ,
                              float* __restrict__ term_x) {
    const int b = blockIdx.x;
    const f32x4* x4 = (const f32x4*)(x + (size_t)b * CIN);
    f16x4* xq4 = (f16x4*)(XQ + (size_t)b * CIN);
    float sum = 0.f;
    for (int i = threadIdx.x; i < CIN / 4; i += 256) {
        f32x4 v = x4[i];
        f16x4 h;
#pragma unroll
        for (int j = 0; j < 4; ++j) {
            float xv = fminf(fmaxf(v[j], 0.f), 1.f);
            float q  = rintf(xv * 255.f) / 255.f;
            h[j] = (_Float16)q;
            float d0 = disks[2 * (4 * i + j)], d1 = disks[2 * (4 * i + j) + 1];
            sum += q * q * (d0 - d1);
        }
        xq4[i] = h;
    }
    sum = wave_reduce_sum(sum);
    __shared__ float red[4];
    if ((threadIdx.x & 63) == 0) red[threadIdx.x >> 6] = sum;
    __syncthreads();
    if (threadIdx.x == 0)
        term_x[b] = 0.25f * (red[0] + red[1] + red[2] + red[3]);
}

// ---------------------------------------------------------------- K4: GEMM
// C[b][o] = 0.5 * sum_k XQ[b][k] * V[o][k] + term_x[b] + term_w[o]
// m97 structure: 128x128 tile, BK=32, 4 waves (2x2), 16x16x32 f16 MFMA,
// global_load_lds width=16, linear LDS.
#define BM 128
#define BN 128
#define BK 32

__global__ void gemm_kernel(const _Float16* __restrict__ A,   // [B_DIM][CIN]
                            const _Float16* __restrict__ Bw,  // [COUT][CIN]
                            const float* __restrict__ term_x, // [B_DIM], pre*0.25
                            const float* __restrict__ term_w, // [COUT], pre*0.25
                            float* __restrict__ C) {          // [B_DIM][COUT]
    __shared__ __align__(16) _Float16 As[BM * BK];
    __shared__ __align__(16) _Float16 Bs[BN * BK];

    const int tid  = threadIdx.x;
    const int wave = tid >> 6;
    const int lane = tid & 63;

    const int tiles_n = COUT / BN;  // 16
    const int tile_n = blockIdx.x % tiles_n;
    const int tile_m = blockIdx.x / tiles_n;

    const int row0 = tile_m * BM;
    const int col0 = tile_n * BN;

    const int wr = wave >> 1;  // 0..1
    const int wc = wave & 1;   // 0..1

    f32x4 acc[4][4];
#pragma unroll
    for (int m = 0; m < 4; ++m)
#pragma unroll
        for (int n = 0; n < 4; ++n)
            acc[m][n] = (f32x4){0.f, 0.f, 0.f, 0.f};

    const int ch_row = lane >> 2;        // row within a 16-row chunk
    const int ch_off = (lane & 3) * 8;   // halves offset (16B granules)

    const _Float16* Ag = A  + (size_t)row0 * CIN;
    const _Float16* Bg = Bw + (size_t)col0 * CIN;

    const int fr = lane & 15;
    const int fq = lane >> 4;

    for (int k0 = 0; k0 < CIN; k0 += BK) {
        // stage: each wave stages chunks {wave, wave+4} of both tiles.
        // LDS dest is wave-uniform base; HW writes lane l at base + 16*l,
        // which matches row-major [128][32] f16 (row = chunk*16 + l/4).
#pragma unroll
        for (int j = 0; j < 2; ++j) {
            const int chunk = wave + j * 4;
            const int r = chunk * 16 + ch_row;
            const _Float16* srcA = Ag + (size_t)r * CIN + k0 + ch_off;
            const _Float16* srcB = Bg + (size_t)r * CIN + k0 + ch_off;
            __builtin_amdgcn_global_load_lds(
                (const __attribute__((address_space(1))) void*)srcA,
                (__attribute__((address_space(3))) void*)(As + chunk * 512),
                16, 0, 0);
            __builtin_amdgcn_global_load_lds(
                (const __attribute__((address_space(1))) void*)srcB,
                (__attribute__((address_space(3))) void*)(Bs + chunk * 512),
                16, 0, 0);
        }
        __syncthreads();  // compiler drains vmcnt before barrier

        f16x8 af[4], bf[4];
#pragma unroll
        for (int m = 0; m < 4; ++m) {
            const int r = wr * 64 + m * 16 + fr;
            af[m] = *(const f16x8*)(As + r * BK + fq * 8);
        }
#pragma unroll
        for (int n = 0; n < 4; ++n) {
            const int c = wc * 64 + n * 16 + fr;
            bf[n] = *(const f16x8*)(Bs + c * BK + fq * 8);
        }
#pragma unroll
        for (int m = 0; m < 4; ++m)
#pragma unroll
            for (int n = 0; n < 4; ++n)
                acc[m][n] = __builtin_amdgcn_mfma_f32_16x16x32_f16(
                    af[m], bf[n], acc[m][n], 0, 0, 0);
        __syncthreads();  // all waves done reading before next stage
    }

    // epilogue: C/D layout col = lane&15, row = (lane>>4)*4 + reg
#pragma unroll
    for (int m = 0; m < 4; ++m) {
        const int rbase = row0 + wr * 64 + m * 16 + fq * 4;
#pragma unroll
        for (int n = 0; n < 4; ++n) {
            const int c = col0 + wc * 64 + n * 16 + fr;
            const float tw = term_w[c];
#pragma unroll
            for (int j = 0; j < 4; ++j) {
                const int r = rbase + j;
                C[(size_t)r * COUT + c] = 0.5f * acc[m][n][j] + term_x[r] + tw;
            }
        }
    }
}

// ---------------------------------------------------------------- launcher
extern "C" void kernel_launch(void* const* d_in, const int* in_sizes, int n_in,
                              void* d_out, int out_size, void* d_ws, size_t ws_size,
                              hipStream_t stream) {
    const float* x      = (const float*)d_in[0];
    const float* weight = (const float*)d_in[1];
    const float* phases = (const float*)d_in[2];
    const float* disks  = (const float*)d_in[3];
    float* out = (float*)d_out;

    char* ws = (char*)d_ws;
    unsigned int* maxbuf = (unsigned int*)ws;                    // 4 B
    float* term_w = (float*)(ws + 1024);                         // 8 KB
    float* term_x = (float*)(ws + 16384);                        // 16 KB
    _Float16* V   = (_Float16*)(ws + 32768);                     // 8 MB
    _Float16* XQ  = (_Float16*)(ws + 32768 + (size_t)COUT * CIN * 2);  // 16 MB

    hipMemsetAsync(maxbuf, 0, 4, stream);
    maxabs_kernel<<<1024, 256, 0, stream>>>(weight, maxbuf);
    prep_w_kernel<<<COUT, 256, 0, stream>>>(weight, phases, disks, maxbuf, V, term_w);
    prep_x_kernel<<<B_DIM, 256, 0, stream>>>(x, disks, XQ, term_x);
    gemm_kernel<<<(B_DIM / BM) * (COUT / BN), 256, 0, stream>>>(XQ, V, term_x, term_w, out);
}

// Round 2
// 81.570 us; speedup vs baseline: 1.1516x; 1.1516x over previous
//
#include <hip/hip_runtime.h>
#include <hip/hip_bf16.h>
#include <math.h>

#define B_DIM 4096
#define CIN   2048
#define COUT  2048

typedef _Float16 f16x8 __attribute__((ext_vector_type(8)));
typedef _Float16 f16x4 __attribute__((ext_vector_type(4)));
typedef float    f32x4 __attribute__((ext_vector_type(4)));

__device__ inline float wave_reduce_sum(float v) {
#pragma unroll
    for (int off = 32; off > 0; off >>= 1)
        v += __shfl_down(v, off, 64);
    return v;
}
__device__ inline float wave_reduce_max(float v) {
#pragma unroll
    for (int off = 32; off > 0; off >>= 1)
        v = fmaxf(v, __shfl_down(v, off, 64));
    return v;
}

// ---------------------------------------------------------------------------
// Kernel A (fused): blocks [0,4096)   : quantize x -> XQ (f16), term_x
//                   blocks [4096,4352): partial max|weight| -> pmax[256]
//                   block  4352       : tables s[i]=sin(phi)*(d0+d1), dd[i]=d0-d1
// ---------------------------------------------------------------------------
#define NMAXBLK 256
__global__ void prep_a_kernel(const float* __restrict__ x,
                              const float* __restrict__ weight,
                              const float* __restrict__ phases,
                              const float* __restrict__ disks,
                              _Float16* __restrict__ XQ,
                              float* __restrict__ term_x,
                              float* __restrict__ pmax,
                              float* __restrict__ s_tab,
                              float* __restrict__ dd_tab) {
    __shared__ float red[4];
    const int blk = blockIdx.x;
    const int tid = threadIdx.x;

    if (blk < B_DIM) {
        const f32x4* x4  = (const f32x4*)(x + (size_t)blk * CIN);
        const f32x4* dk  = (const f32x4*)disks;   // [CIN][2] interleaved
        f16x4* xq4 = (f16x4*)(XQ + (size_t)blk * CIN);
        float sum = 0.f;
        for (int g = tid; g < CIN / 4; g += 256) {
            f32x4 v   = x4[g];
            f32x4 dv0 = dk[2 * g];
            f32x4 dv1 = dk[2 * g + 1];
            float dd0 = dv0[0] - dv0[1], dd1 = dv0[2] - dv0[3];
            float dd2 = dv1[0] - dv1[1], dd3 = dv1[2] - dv1[3];
            f16x4 h;
            float q0 = rintf(fminf(fmaxf(v[0], 0.f), 1.f) * 255.f) * (1.f / 255.f);
            float q1 = rintf(fminf(fmaxf(v[1], 0.f), 1.f) * 255.f) * (1.f / 255.f);
            float q2 = rintf(fminf(fmaxf(v[2], 0.f), 1.f) * 255.f) * (1.f / 255.f);
            float q3 = rintf(fminf(fmaxf(v[3], 0.f), 1.f) * 255.f) * (1.f / 255.f);
            h[0] = (_Float16)q0; h[1] = (_Float16)q1;
            h[2] = (_Float16)q2; h[3] = (_Float16)q3;
            xq4[g] = h;
            sum += q0 * q0 * dd0 + q1 * q1 * dd1 + q2 * q2 * dd2 + q3 * q3 * dd3;
        }
        sum = wave_reduce_sum(sum);
        if ((tid & 63) == 0) red[tid >> 6] = sum;
        __syncthreads();
        if (tid == 0)
            term_x[blk] = 0.25f * (red[0] + red[1] + red[2] + red[3]);
    } else if (blk < B_DIM + NMAXBLK) {
        const int mb = blk - B_DIM;
        const size_t n4 = (size_t)COUT * CIN / 4;
        const f32x4* w4 = (const f32x4*)weight;
        float m = 0.f;
        for (size_t i = (size_t)mb * 256 + tid; i < n4; i += (size_t)NMAXBLK * 256) {
            f32x4 v = w4[i];
            m = fmaxf(m, fmaxf(fmaxf(fabsf(v[0]), fabsf(v[1])),
                               fmaxf(fabsf(v[2]), fabsf(v[3]))));
        }
        m = wave_reduce_max(m);
        if ((tid & 63) == 0) red[tid >> 6] = m;
        __syncthreads();
        if (tid == 0)
            pmax[mb] = fmaxf(fmaxf(red[0], red[1]), fmaxf(red[2], red[3]));
    } else {
        for (int i = tid; i < CIN; i += 256) {
            float d0 = disks[2 * i], d1 = disks[2 * i + 1];
            s_tab[i]  = sinf(phases[i]) * (d0 + d1);
            dd_tab[i] = d0 - d1;
        }
    }
}

// ---------------------------------------------------------------------------
// Kernel B: per-row weight quantize -> V = wq * s (f16), term_w
// ---------------------------------------------------------------------------
__global__ void prep_b_kernel(const float* __restrict__ weight,
                              const float* __restrict__ pmax,
                              const float* __restrict__ s_tab,
                              const float* __restrict__ dd_tab,
                              _Float16* __restrict__ V,
                              float* __restrict__ term_w) {
    __shared__ float red[4];
    __shared__ float bmax;
    const int tid = threadIdx.x;

    float m = pmax[tid];                         // 256 threads, 256 partials
    m = wave_reduce_max(m);
    if ((tid & 63) == 0) red[tid >> 6] = m;
    __syncthreads();
    if (tid == 0)
        bmax = tanhf(fmaxf(fmaxf(red[0], red[1]), fmaxf(red[2], red[3])));
    __syncthreads();
    const float inv2m = 0.5f / bmax;             // max|tanh(W)| = tanh(max|W|)

    const int o = blockIdx.x;
    const f32x4* w4  = (const f32x4*)(weight + (size_t)o * CIN);
    const f32x4* s4  = (const f32x4*)s_tab;
    const f32x4* dd4 = (const f32x4*)dd_tab;
    f16x4* v4 = (f16x4*)(V + (size_t)o * CIN);
    float sum = 0.f;
    for (int g = tid; g < CIN / 4; g += 256) {
        f32x4 wv = w4[g], sv = s4[g], ddv = dd4[g];
        f16x4 h;
#pragma unroll
        for (int j = 0; j < 4; ++j) {
            float t  = tanhf(wv[j]);
            float wq = rintf((t * inv2m + 0.5f) * 255.f) * (1.f / 255.f);
            sum += wq * wq * ddv[j];
            h[j] = (_Float16)(wq * sv[j]);
        }
        v4[g] = h;
    }
    sum = wave_reduce_sum(sum);
    __syncthreads();                             // red reused
    if ((tid & 63) == 0) red[tid >> 6] = sum;
    __syncthreads();
    if (tid == 0)
        term_w[o] = 0.25f * (red[0] + red[1] + red[2] + red[3]);
}

// ---------------------------------------------------------------------------
// Kernel C: GEMM  C[b][o] = 0.5*sum_k XQ[b][k]*V[o][k] + term_x[b] + term_w[o]
// 128x128 tile, BK=32, 4 waves (2x2), 16x16x32 f16 MFMA.
// Double-buffered LDS (T3-minimum 2-phase: STAGE(next) issued before compute,
// ONE barrier per K-step) + 16B-granule XOR swizzle (q ^ (row&3)) applied
// both-sides: pre-swizzled global source (linear global_load_lds dest) +
// swizzled ds_read address. 8-way bank conflict -> 2-way (free).
// ---------------------------------------------------------------------------
#define BM 128
#define BN 128
#define BK 32
#define NT (CIN / BK)

__global__ __launch_bounds__(256) void
gemm_kernel(const _Float16* __restrict__ A,   // [B_DIM][CIN]
            const _Float16* __restrict__ Bw,  // [COUT][CIN]
            const float* __restrict__ term_x, // pre*0.25
            const float* __restrict__ term_w, // pre*0.25
            float* __restrict__ C) {
    __shared__ __align__(16) _Float16 As[2][BM * BK];
    __shared__ __align__(16) _Float16 Bs[2][BN * BK];

    const int tid  = threadIdx.x;
    const int wave = tid >> 6;
    const int lane = tid & 63;

    const int tiles_n = COUT / BN;  // 16
    const int tile_n = blockIdx.x % tiles_n;
    const int tile_m = blockIdx.x / tiles_n;
    const int row0 = tile_m * BM;
    const int col0 = tile_n * BN;
    const int wr = wave >> 1;
    const int wc = wave & 1;

    f32x4 acc[4][4];
#pragma unroll
    for (int m = 0; m < 4; ++m)
#pragma unroll
        for (int n = 0; n < 4; ++n)
            acc[m][n] = (f32x4){0.f, 0.f, 0.f, 0.f};

    // staging geometry: lane l -> row chunk*16 + (l>>2), 16B granule (l&3).
    // source granule pre-swizzled: fetch logical q = (l&3) ^ (row&3) so that
    // linear LDS slot (row, qp) holds logical granule qp ^ (row&3).
    const int ch_row = lane >> 2;
    const int ch_off = ((lane & 3) ^ (ch_row & 3)) * 8;   // elements

    const _Float16* Ag = A  + (size_t)row0 * CIN;
    const _Float16* Bg = Bw + (size_t)col0 * CIN;

    const int fr = lane & 15;
    const int fq = lane >> 4;
    const int qa = fq ^ (fr & 3);   // physical granule for fragment reads

    auto stage = [&](int buf, int k0) {
#pragma unroll
        for (int j = 0; j < 2; ++j) {
            const int chunk = wave + j * 4;           // wave-uniform
            const int r = chunk * 16 + ch_row;
            __builtin_amdgcn_global_load_lds(
                (const __attribute__((address_space(1))) void*)(Ag + (size_t)r * CIN + k0 + ch_off),
                (__attribute__((address_space(3))) void*)(&As[buf][chunk * 512]),
                16, 0, 0);
            __builtin_amdgcn_global_load_lds(
                (const __attribute__((address_space(1))) void*)(Bg + (size_t)r * CIN + k0 + ch_off),
                (__attribute__((address_space(3))) void*)(&Bs[buf][chunk * 512]),
                16, 0, 0);
        }
    };

    stage(0, 0);
    __syncthreads();

    int cur = 0;
    for (int t = 0; t < NT; ++t) {
        if (t + 1 < NT) stage(cur ^ 1, (t + 1) * BK);   // prefetch overlaps compute

        f16x8 af[4], bf[4];
#pragma unroll
        for (int m = 0; m < 4; ++m) {
            const int r = wr * 64 + m * 16 + fr;
            af[m] = *(const f16x8*)(&As[cur][r * BK + qa * 8]);
        }
#pragma unroll
        for (int n = 0; n < 4; ++n) {
            const int c = wc * 64 + n * 16 + fr;
            bf[n] = *(const f16x8*)(&Bs[cur][c * BK + qa * 8]);
        }
#pragma unroll
        for (int m = 0; m < 4; ++m)
#pragma unroll
            for (int n = 0; n < 4; ++n)
                acc[m][n] = __builtin_amdgcn_mfma_f32_16x16x32_f16(
                    af[m], bf[n], acc[m][n], 0, 0, 0);

        __syncthreads();   // drains vmcnt(0): prefetched tile ready; LDS reads done
        cur ^= 1;
    }

    // epilogue: C/D layout col = lane&15, row = (lane>>4)*4 + reg
#pragma unroll
    for (int m = 0; m < 4; ++m) {
        const int rbase = row0 + wr * 64 + m * 16 + fq * 4;
#pragma unroll
        for (int n = 0; n < 4; ++n) {
            const int c = col0 + wc * 64 + n * 16 + fr;
            const float tw = term_w[c];
#pragma unroll
            for (int j = 0; j < 4; ++j) {
                const int r = rbase + j;
                C[(size_t)r * COUT + c] = 0.5f * acc[m][n][j] + term_x[r] + tw;
            }
        }
    }
}

// ---------------------------------------------------------------- launcher
extern "C" void kernel_launch(void* const* d_in, const int* in_sizes, int n_in,
                              void* d_out, int out_size, void* d_ws, size_t ws_size,
                              hipStream_t stream) {
    const float* x      = (const float*)d_in[0];
    const float* weight = (const float*)d_in[1];
    const float* phases = (const float*)d_in[2];
    const float* disks  = (const float*)d_in[3];
    float* out = (float*)d_out;

    char* ws = (char*)d_ws;
    float* pmax   = (float*)(ws);                    // 1 KB
    float* s_tab  = (float*)(ws + 4096);             // 8 KB
    float* dd_tab = (float*)(ws + 16384);            // 8 KB
    float* term_w = (float*)(ws + 32768);            // 8 KB
    float* term_x = (float*)(ws + 49152);            // 16 KB
    _Float16* V   = (_Float16*)(ws + 65536);                               // 8 MB
    _Float16* XQ  = (_Float16*)(ws + 65536 + (size_t)COUT * CIN * 2);      // 16 MB

    prep_a_kernel<<<B_DIM + NMAXBLK + 1, 256, 0, stream>>>(
        x, weight, phases, disks, XQ, term_x, pmax, s_tab, dd_tab);
    prep_b_kernel<<<COUT, 256, 0, stream>>>(weight, pmax, s_tab, dd_tab, V, term_w);
    gemm_kernel<<<(B_DIM / BM) * (COUT / BN), 256, 0, stream>>>(XQ, V, term_x, term_w, out);
}

// Round 3
// 69.185 us; speedup vs baseline: 1.3577x; 1.1790x over previous
//
#include <hip/hip_runtime.h>
#include <hip/hip_bf16.h>
#include <math.h>

#define B_DIM 4096
#define CIN   2048
#define COUT  2048

typedef _Float16 f16x8 __attribute__((ext_vector_type(8)));
typedef _Float16 f16x4 __attribute__((ext_vector_type(4)));
typedef float    f32x4 __attribute__((ext_vector_type(4)));

__device__ inline float wave_reduce_sum(float v) {
#pragma unroll
    for (int off = 32; off > 0; off >>= 1)
        v += __shfl_down(v, off, 64);
    return v;
}
__device__ inline float wave_reduce_max(float v) {
#pragma unroll
    for (int off = 32; off > 0; off >>= 1)
        v = fmaxf(v, __shfl_down(v, off, 64));
    return v;
}

// ---------------------------------------------------------------------------
// Kernel A (fused): blocks [0,4096)   : quantize x -> XQ (f16), term_x
//                   blocks [4096,4352): partial max|weight| -> pmax[256]
//                   block  4352       : tables s[i]=sin(phi)*(d0+d1), dd[i]=d0-d1
// ---------------------------------------------------------------------------
#define NMAXBLK 256
__global__ void prep_a_kernel(const float* __restrict__ x,
                              const float* __restrict__ weight,
                              const float* __restrict__ phases,
                              const float* __restrict__ disks,
                              _Float16* __restrict__ XQ,
                              float* __restrict__ term_x,
                              float* __restrict__ pmax,
                              float* __restrict__ s_tab,
                              float* __restrict__ dd_tab) {
    __shared__ float red[4];
    const int blk = blockIdx.x;
    const int tid = threadIdx.x;

    if (blk < B_DIM) {
        const f32x4* x4  = (const f32x4*)(x + (size_t)blk * CIN);
        const f32x4* dk  = (const f32x4*)disks;   // [CIN][2] interleaved
        f16x4* xq4 = (f16x4*)(XQ + (size_t)blk * CIN);
        float sum = 0.f;
        for (int g = tid; g < CIN / 4; g += 256) {
            f32x4 v   = x4[g];
            f32x4 dv0 = dk[2 * g];
            f32x4 dv1 = dk[2 * g + 1];
            float dd0 = dv0[0] - dv0[1], dd1 = dv0[2] - dv0[3];
            float dd2 = dv1[0] - dv1[1], dd3 = dv1[2] - dv1[3];
            f16x4 h;
            float q0 = rintf(fminf(fmaxf(v[0], 0.f), 1.f) * 255.f) * (1.f / 255.f);
            float q1 = rintf(fminf(fmaxf(v[1], 0.f), 1.f) * 255.f) * (1.f / 255.f);
            float q2 = rintf(fminf(fmaxf(v[2], 0.f), 1.f) * 255.f) * (1.f / 255.f);
            float q3 = rintf(fminf(fmaxf(v[3], 0.f), 1.f) * 255.f) * (1.f / 255.f);
            h[0] = (_Float16)q0; h[1] = (_Float16)q1;
            h[2] = (_Float16)q2; h[3] = (_Float16)q3;
            xq4[g] = h;
            sum += q0 * q0 * dd0 + q1 * q1 * dd1 + q2 * q2 * dd2 + q3 * q3 * dd3;
        }
        sum = wave_reduce_sum(sum);
        if ((tid & 63) == 0) red[tid >> 6] = sum;
        __syncthreads();
        if (tid == 0)
            term_x[blk] = 0.25f * (red[0] + red[1] + red[2] + red[3]);
    } else if (blk < B_DIM + NMAXBLK) {
        const int mb = blk - B_DIM;
        const size_t n4 = (size_t)COUT * CIN / 4;
        const f32x4* w4 = (const f32x4*)weight;
        float m = 0.f;
        for (size_t i = (size_t)mb * 256 + tid; i < n4; i += (size_t)NMAXBLK * 256) {
            f32x4 v = w4[i];
            m = fmaxf(m, fmaxf(fmaxf(fabsf(v[0]), fabsf(v[1])),
                               fmaxf(fabsf(v[2]), fabsf(v[3]))));
        }
        m = wave_reduce_max(m);
        if ((tid & 63) == 0) red[tid >> 6] = m;
        __syncthreads();
        if (tid == 0)
            pmax[mb] = fmaxf(fmaxf(red[0], red[1]), fmaxf(red[2], red[3]));
    } else {
        for (int i = tid; i < CIN; i += 256) {
            float d0 = disks[2 * i], d1 = disks[2 * i + 1];
            s_tab[i]  = sinf(phases[i]) * (d0 + d1);
            dd_tab[i] = d0 - d1;
        }
    }
}

// ---------------------------------------------------------------------------
// Kernel B: per-row weight quantize -> V = wq * s (f16), term_w
// ---------------------------------------------------------------------------
__global__ void prep_b_kernel(const float* __restrict__ weight,
                              const float* __restrict__ pmax,
                              const float* __restrict__ s_tab,
                              const float* __restrict__ dd_tab,
                              _Float16* __restrict__ V,
                              float* __restrict__ term_w) {
    __shared__ float red[4];
    __shared__ float bmax;
    const int tid = threadIdx.x;

    float m = pmax[tid];                         // 256 threads, 256 partials
    m = wave_reduce_max(m);
    if ((tid & 63) == 0) red[tid >> 6] = m;
    __syncthreads();
    if (tid == 0)
        bmax = tanhf(fmaxf(fmaxf(red[0], red[1]), fmaxf(red[2], red[3])));
    __syncthreads();
    const float inv2m = 0.5f / bmax;             // max|tanh(W)| = tanh(max|W|)

    const int o = blockIdx.x;
    const f32x4* w4  = (const f32x4*)(weight + (size_t)o * CIN);
    const f32x4* s4  = (const f32x4*)s_tab;
    const f32x4* dd4 = (const f32x4*)dd_tab;
    f16x4* v4 = (f16x4*)(V + (size_t)o * CIN);
    float sum = 0.f;
    for (int g = tid; g < CIN / 4; g += 256) {
        f32x4 wv = w4[g], sv = s4[g], ddv = dd4[g];
        f16x4 h;
#pragma unroll
        for (int j = 0; j < 4; ++j) {
            float t  = tanhf(wv[j]);
            float wq = rintf((t * inv2m + 0.5f) * 255.f) * (1.f / 255.f);
            sum += wq * wq * ddv[j];
            h[j] = (_Float16)(wq * sv[j]);
        }
        v4[g] = h;
    }
    sum = wave_reduce_sum(sum);
    __syncthreads();                             // red reused
    if ((tid & 63) == 0) red[tid >> 6] = sum;
    __syncthreads();
    if (tid == 0)
        term_w[o] = 0.25f * (red[0] + red[1] + red[2] + red[3]);
}

// ---------------------------------------------------------------------------
// Kernel C: GEMM  C[b][o] = 0.5*sum_k XQ[b][k]*V[o][k] + term_x[b] + term_w[o]
// 128x128 tile, BK=64, 4 waves (2x2), 16x16x32 f16 MFMA.
// m97 structure (single buffer, 2 barriers/K-step, loop-invariant LDS addrs)
// + 8-way 16B-granule XOR swizzle, both-sides:
//   LDS slot (row, pg) holds logical granule g = pg ^ (row&7).
//   stage: linear global_load_lds dest; global source granule pre-swizzled.
//   read : logical granule g of row r at physical pg = g ^ (r&7).
// With 128B rows, bank = pg*4 .. pg*4+3 -> 64-lane b128 spreads 8 lanes per
// 4-bank group, distinct addresses = structural minimum (8 service cycles).
// ---------------------------------------------------------------------------
#define BM 128
#define BN 128
#define BK 64
#define NT (CIN / BK)   // 32

__global__ __launch_bounds__(256) void
gemm_kernel(const _Float16* __restrict__ A,   // [B_DIM][CIN]
            const _Float16* __restrict__ Bw,  // [COUT][CIN]
            const float* __restrict__ term_x, // pre*0.25
            const float* __restrict__ term_w, // pre*0.25
            float* __restrict__ C) {
    __shared__ __align__(16) _Float16 As[BM * BK];  // 16 KB
    __shared__ __align__(16) _Float16 Bs[BN * BK];  // 16 KB

    const int tid  = threadIdx.x;
    const int wave = tid >> 6;
    const int lane = tid & 63;

    const int tiles_n = COUT / BN;  // 16
    const int tile_n = blockIdx.x % tiles_n;
    const int tile_m = blockIdx.x / tiles_n;
    const int row0 = tile_m * BM;
    const int col0 = tile_n * BN;
    const int wr = wave >> 1;
    const int wc = wave & 1;

    f32x4 acc[4][4];
#pragma unroll
    for (int m = 0; m < 4; ++m)
#pragma unroll
        for (int n = 0; n < 4; ++n)
            acc[m][n] = (f32x4){0.f, 0.f, 0.f, 0.f};

    // staging: chunk = 8 rows x 64 f16 = 1 KB = one global_load_lds per wave.
    // lane l -> row l>>3, physical granule l&7; source fetches logical
    // granule (l&7) ^ (l>>3 & 7)  (involution with the read swizzle).
    const int st_row = lane >> 3;                      // 0..7
    const int st_col = ((lane & 7) ^ (st_row & 7)) * 8;  // elements

    const _Float16* Ag = A  + (size_t)row0 * CIN;
    const _Float16* Bg = Bw + (size_t)col0 * CIN;

    const int fr = lane & 15;
    const int fq = lane >> 4;      // 0..3
    const int h  = fr & 7;

    // loop-invariant LDS read offsets (elements), per m and k-slice s:
    //   off = r*64 + ((s*4+fq)^h)*8,  r = wr*64 + m*16 + fr
    int offA[2][4], offB[2][4];
#pragma unroll
    for (int s = 0; s < 2; ++s)
#pragma unroll
        for (int m = 0; m < 4; ++m) {
            const int ra = wr * 64 + m * 16 + fr;
            const int cb = wc * 64 + m * 16 + fr;
            const int pg = (s * 4 + fq) ^ h;
            offA[s][m] = ra * BK + pg * 8;
            offB[s][m] = cb * BK + pg * 8;
        }

    for (int k0 = 0; k0 < CIN; k0 += BK) {
#pragma unroll
        for (int j = 0; j < 4; ++j) {
            const int chunk = wave + j * 4;            // wave-uniform, 0..15
            const int r = chunk * 8 + st_row;
            __builtin_amdgcn_global_load_lds(
                (const __attribute__((address_space(1))) void*)(Ag + (size_t)r * CIN + k0 + st_col),
                (__attribute__((address_space(3))) void*)(As + chunk * 512),
                16, 0, 0);
            __builtin_amdgcn_global_load_lds(
                (const __attribute__((address_space(1))) void*)(Bg + (size_t)r * CIN + k0 + st_col),
                (__attribute__((address_space(3))) void*)(Bs + chunk * 512),
                16, 0, 0);
        }
        __syncthreads();   // drains vmcnt: tile resident

#pragma unroll
        for (int s = 0; s < 2; ++s) {
            f16x8 af[4], bf[4];
#pragma unroll
            for (int m = 0; m < 4; ++m) af[m] = *(const f16x8*)(As + offA[s][m]);
#pragma unroll
            for (int n = 0; n < 4; ++n) bf[n] = *(const f16x8*)(Bs + offB[s][n]);
#pragma unroll
            for (int m = 0; m < 4; ++m)
#pragma unroll
                for (int n = 0; n < 4; ++n)
                    acc[m][n] = __builtin_amdgcn_mfma_f32_16x16x32_f16(
                        af[m], bf[n], acc[m][n], 0, 0, 0);
        }
        __syncthreads();   // all waves done reading before next stage
    }

    // epilogue: C/D layout col = lane&15, row = (lane>>4)*4 + reg
#pragma unroll
    for (int m = 0; m < 4; ++m) {
        const int rbase = row0 + wr * 64 + m * 16 + fq * 4;
#pragma unroll
        for (int n = 0; n < 4; ++n) {
            const int c = col0 + wc * 64 + n * 16 + fr;
            const float tw = term_w[c];
#pragma unroll
            for (int j = 0; j < 4; ++j) {
                const int r = rbase + j;
                C[(size_t)r * COUT + c] = 0.5f * acc[m][n][j] + term_x[r] + tw;
            }
        }
    }
}

// ---------------------------------------------------------------- launcher
extern "C" void kernel_launch(void* const* d_in, const int* in_sizes, int n_in,
                              void* d_out, int out_size, void* d_ws, size_t ws_size,
                              hipStream_t stream) {
    const float* x      = (const float*)d_in[0];
    const float* weight = (const float*)d_in[1];
    const float* phases = (const float*)d_in[2];
    const float* disks  = (const float*)d_in[3];
    float* out = (float*)d_out;

    char* ws = (char*)d_ws;
    float* pmax   = (float*)(ws);                    // 1 KB
    float* s_tab  = (float*)(ws + 4096);             // 8 KB
    float* dd_tab = (float*)(ws + 16384);            // 8 KB
    float* term_w = (float*)(ws + 32768);            // 8 KB
    float* term_x = (float*)(ws + 49152);            // 16 KB
    _Float16* V   = (_Float16*)(ws + 65536);                               // 8 MB
    _Float16* XQ  = (_Float16*)(ws + 65536 + (size_t)COUT * CIN * 2);      // 16 MB

    prep_a_kernel<<<B_DIM + NMAXBLK + 1, 256, 0, stream>>>(
        x, weight, phases, disks, XQ, term_x, pmax, s_tab, dd_tab);
    prep_b_kernel<<<COUT, 256, 0, stream>>>(weight, pmax, s_tab, dd_tab, V, term_w);
    gemm_kernel<<<(B_DIM / BM) * (COUT / BN), 256, 0, stream>>>(XQ, V, term_x, term_w, out);
}

// Round 4
// 67.300 us; speedup vs baseline: 1.3958x; 1.0280x over previous
//
#include <hip/hip_runtime.h>
#include <hip/hip_bf16.h>
#include <math.h>

#define B_DIM 4096
#define CIN   2048
#define COUT  2048

typedef _Float16 f16x8 __attribute__((ext_vector_type(8)));
typedef _Float16 f16x4 __attribute__((ext_vector_type(4)));
typedef float    f32x4 __attribute__((ext_vector_type(4)));

__device__ inline float wave_reduce_sum(float v) {
#pragma unroll
    for (int off = 32; off > 0; off >>= 1)
        v += __shfl_down(v, off, 64);
    return v;
}
__device__ inline float wave_reduce_max(float v) {
#pragma unroll
    for (int off = 32; off > 0; off >>= 1)
        v = fmaxf(v, __shfl_down(v, off, 64));
    return v;
}

// ---------------------------------------------------------------------------
// Kernel A (fused): blocks [0,4096)   : quantize x -> XQ (f16), term_x
//                   blocks [4096,4352): partial max|weight| -> pmax[256]
//                   block  4352       : tables s[i]=sin(phi)*(d0+d1), dd[i]=d0-d1
// ---------------------------------------------------------------------------
#define NMAXBLK 256
__global__ void prep_a_kernel(const float* __restrict__ x,
                              const float* __restrict__ weight,
                              const float* __restrict__ phases,
                              const float* __restrict__ disks,
                              _Float16* __restrict__ XQ,
                              float* __restrict__ term_x,
                              float* __restrict__ pmax,
                              float* __restrict__ s_tab,
                              float* __restrict__ dd_tab) {
    __shared__ float red[4];
    const int blk = blockIdx.x;
    const int tid = threadIdx.x;

    if (blk < B_DIM) {
        const f32x4* x4  = (const f32x4*)(x + (size_t)blk * CIN);
        const f32x4* dk  = (const f32x4*)disks;   // [CIN][2] interleaved
        f16x4* xq4 = (f16x4*)(XQ + (size_t)blk * CIN);
        float sum = 0.f;
        for (int g = tid; g < CIN / 4; g += 256) {
            f32x4 v   = x4[g];
            f32x4 dv0 = dk[2 * g];
            f32x4 dv1 = dk[2 * g + 1];
            float dd0 = dv0[0] - dv0[1], dd1 = dv0[2] - dv0[3];
            float dd2 = dv1[0] - dv1[1], dd3 = dv1[2] - dv1[3];
            f16x4 h;
            float q0 = rintf(fminf(fmaxf(v[0], 0.f), 1.f) * 255.f) * (1.f / 255.f);
            float q1 = rintf(fminf(fmaxf(v[1], 0.f), 1.f) * 255.f) * (1.f / 255.f);
            float q2 = rintf(fminf(fmaxf(v[2], 0.f), 1.f) * 255.f) * (1.f / 255.f);
            float q3 = rintf(fminf(fmaxf(v[3], 0.f), 1.f) * 255.f) * (1.f / 255.f);
            h[0] = (_Float16)q0; h[1] = (_Float16)q1;
            h[2] = (_Float16)q2; h[3] = (_Float16)q3;
            xq4[g] = h;
            sum += q0 * q0 * dd0 + q1 * q1 * dd1 + q2 * q2 * dd2 + q3 * q3 * dd3;
        }
        sum = wave_reduce_sum(sum);
        if ((tid & 63) == 0) red[tid >> 6] = sum;
        __syncthreads();
        if (tid == 0)
            term_x[blk] = 0.25f * (red[0] + red[1] + red[2] + red[3]);
    } else if (blk < B_DIM + NMAXBLK) {
        const int mb = blk - B_DIM;
        const size_t n4 = (size_t)COUT * CIN / 4;
        const f32x4* w4 = (const f32x4*)weight;
        float m = 0.f;
        for (size_t i = (size_t)mb * 256 + tid; i < n4; i += (size_t)NMAXBLK * 256) {
            f32x4 v = w4[i];
            m = fmaxf(m, fmaxf(fmaxf(fabsf(v[0]), fabsf(v[1])),
                               fmaxf(fabsf(v[2]), fabsf(v[3]))));
        }
        m = wave_reduce_max(m);
        if ((tid & 63) == 0) red[tid >> 6] = m;
        __syncthreads();
        if (tid == 0)
            pmax[mb] = fmaxf(fmaxf(red[0], red[1]), fmaxf(red[2], red[3]));
    } else {
        for (int i = tid; i < CIN; i += 256) {
            float d0 = disks[2 * i], d1 = disks[2 * i + 1];
            s_tab[i]  = sinf(phases[i]) * (d0 + d1);
            dd_tab[i] = d0 - d1;
        }
    }
}

// ---------------------------------------------------------------------------
// Kernel B: per-row weight quantize -> V = wq * s (f16), term_w
// ---------------------------------------------------------------------------
__global__ void prep_b_kernel(const float* __restrict__ weight,
                              const float* __restrict__ pmax,
                              const float* __restrict__ s_tab,
                              const float* __restrict__ dd_tab,
                              _Float16* __restrict__ V,
                              float* __restrict__ term_w) {
    __shared__ float red[4];
    __shared__ float bmax;
    const int tid = threadIdx.x;

    float m = pmax[tid];
    m = wave_reduce_max(m);
    if ((tid & 63) == 0) red[tid >> 6] = m;
    __syncthreads();
    if (tid == 0)
        bmax = tanhf(fmaxf(fmaxf(red[0], red[1]), fmaxf(red[2], red[3])));
    __syncthreads();
    const float inv2m = 0.5f / bmax;             // max|tanh(W)| = tanh(max|W|)

    const int o = blockIdx.x;
    const f32x4* w4  = (const f32x4*)(weight + (size_t)o * CIN);
    const f32x4* s4  = (const f32x4*)s_tab;
    const f32x4* dd4 = (const f32x4*)dd_tab;
    f16x4* v4 = (f16x4*)(V + (size_t)o * CIN);
    float sum = 0.f;
    for (int g = tid; g < CIN / 4; g += 256) {
        f32x4 wv = w4[g], sv = s4[g], ddv = dd4[g];
        f16x4 h;
#pragma unroll
        for (int j = 0; j < 4; ++j) {
            float t  = tanhf(wv[j]);
            float wq = rintf((t * inv2m + 0.5f) * 255.f) * (1.f / 255.f);
            sum += wq * wq * ddv[j];
            h[j] = (_Float16)(wq * sv[j]);
        }
        v4[g] = h;
    }
    sum = wave_reduce_sum(sum);
    __syncthreads();
    if ((tid & 63) == 0) red[tid >> 6] = sum;
    __syncthreads();
    if (tid == 0)
        term_w[o] = 0.25f * (red[0] + red[1] + red[2] + red[3]);
}

// ---------------------------------------------------------------------------
// Kernel C: GEMM  C[b][o] = 0.5*sum_k XQ[b][k]*V[o][k] + term_x[b] + term_w[o]
// 8-phase-style deep pipeline (T3+T4+T5): BM=256 BN=128 BK=64, 8 waves (4Mx2N),
// TRIPLE-buffered LDS (144KB, 1 block/CU). Tile t+2 stages during tile t ->
// end-of-tile wait is vmcnt(6) (t+2's 6 loads stay in flight; no drain-to-0
// in the main loop). Raw s_barrier (no implicit vmcnt(0)). XOR-granule
// swizzle both-sides (verified round 3: 0 bank conflicts).
// Per-wave load order: [tile t+1: 6 loads @ tile t-1], [tile t+2: 4 (ph0) + 2
// (ph1) @ tile t] -> vmcnt(6) at end of tile t guarantees t+1 landed; the
// barrier after it publishes all waves' loads. Buffer n2=(t+2)%3 is write-safe
// at tile t ph0: its last readers (tile t-1) finished ds_reads before their
// MFMA (compiler lgkm wait) which precedes the end-of-tile barrier.
// ---------------------------------------------------------------------------
#define BM 256
#define BN 128
#define BK 64
#define NT (CIN / BK)        // 32
#define TILES_N (COUT / BN)  // 16

#define MEMFENCE asm volatile("" ::: "memory")
#define BARRIER() do { MEMFENCE; __builtin_amdgcn_s_barrier(); MEMFENCE; } while (0)
#define VMCNT(N) asm volatile("s_waitcnt vmcnt(" #N ")" ::: "memory")

__global__ __launch_bounds__(512, 2) void
gemm_kernel(const _Float16* __restrict__ A,   // [B_DIM][CIN]
            const _Float16* __restrict__ Bw,  // [COUT][CIN]
            const float* __restrict__ term_x, // pre*0.25
            const float* __restrict__ term_w, // pre*0.25
            float* __restrict__ C) {
    __shared__ __align__(16) _Float16 As[3][BM * BK];  // 3 x 32 KB
    __shared__ __align__(16) _Float16 Bs[3][BN * BK];  // 3 x 16 KB

    const int tid  = threadIdx.x;
    const int wave = tid >> 6;
    const int lane = tid & 63;

    const int tile_m = blockIdx.x / TILES_N;
    const int tile_n = blockIdx.x % TILES_N;
    const int row0 = tile_m * BM;
    const int col0 = tile_n * BN;
    const int wr = wave >> 1;   // 0..3 (M)
    const int wc = wave & 1;    // 0..1 (N)

    f32x4 acc[4][4];
#pragma unroll
    for (int m = 0; m < 4; ++m)
#pragma unroll
        for (int n = 0; n < 4; ++n)
            acc[m][n] = (f32x4){0.f, 0.f, 0.f, 0.f};

    // staging: chunk = 8 rows x 64 f16 = 1 KB = one global_load_lds per wave.
    // lane l -> row l>>3, phys granule l&7; source fetches logical granule
    // (l&7)^(row&7)  (involution with the read swizzle).
    const int st_row = lane >> 3;
    const int st_col = ((lane & 7) ^ (st_row & 7)) * 8;
    const _Float16* Agp = A  + (size_t)row0 * CIN;
    const _Float16* Bgp = Bw + (size_t)col0 * CIN;

    const int fr = lane & 15;
    const int fq = lane >> 4;      // 0..3
    const int hh = fr & 7;

    // loop-invariant LDS read offsets (elements): logical granule ks*4+fq of
    // row r lives at physical granule (ks*4+fq)^(r&7).
    int offA[2][4], offB[2][4];
#pragma unroll
    for (int s = 0; s < 2; ++s)
#pragma unroll
        for (int m = 0; m < 4; ++m) {
            offA[s][m] = (wr * 64 + m * 16 + fr) * BK + (((s * 4 + fq) ^ hh) * 8);
            offB[s][m] = (wc * 64 + m * 16 + fr) * BK + (((s * 4 + fq) ^ hh) * 8);
        }

#define STAGE_A(buf, k0) do {                                                  \
    _Pragma("unroll")                                                          \
    for (int j = 0; j < 4; ++j) {                                              \
        const int chunk = wave + j * 8;     /* 32 chunks cover 256 rows */     \
        const int rr = chunk * 8 + st_row;                                     \
        __builtin_amdgcn_global_load_lds(                                      \
            (const __attribute__((address_space(1))) void*)(Agp + (size_t)rr * CIN + (k0) + st_col), \
            (__attribute__((address_space(3))) void*)(&As[buf][chunk * 512]),  \
            16, 0, 0);                                                         \
    } } while (0)

#define STAGE_B(buf, k0) do {                                                  \
    _Pragma("unroll")                                                          \
    for (int j = 0; j < 2; ++j) {                                              \
        const int chunk = wave + j * 8;     /* 16 chunks cover 128 rows */     \
        const int rr = chunk * 8 + st_row;                                     \
        __builtin_amdgcn_global_load_lds(                                      \
            (const __attribute__((address_space(1))) void*)(Bgp + (size_t)rr * CIN + (k0) + st_col), \
            (__attribute__((address_space(3))) void*)(&Bs[buf][chunk * 512]),  \
            16, 0, 0);                                                         \
    } } while (0)

#define PHASE(bufc, ks, STAGE_STMT, VM_STMT) do {                              \
    STAGE_STMT;                                                                \
    f16x8 af[4], bf[4];                                                        \
    _Pragma("unroll")                                                          \
    for (int m = 0; m < 4; ++m)                                                \
        af[m] = *(const f16x8*)(&As[bufc][offA[ks][m]]);                       \
    _Pragma("unroll")                                                          \
    for (int n = 0; n < 4; ++n)                                                \
        bf[n] = *(const f16x8*)(&Bs[bufc][offB[ks][n]]);                       \
    VM_STMT;                                                                   \
    BARRIER();                                                                 \
    __builtin_amdgcn_sched_barrier(0);                                         \
    __builtin_amdgcn_s_setprio(1);                                             \
    _Pragma("unroll")                                                          \
    for (int m = 0; m < 4; ++m)                                                \
        _Pragma("unroll")                                                      \
        for (int n = 0; n < 4; ++n)                                            \
            acc[m][n] = __builtin_amdgcn_mfma_f32_16x16x32_f16(                \
                af[m], bf[n], acc[m][n], 0, 0, 0);                             \
    __builtin_amdgcn_s_setprio(0);                                             \
    BARRIER();                                                                 \
} while (0)

#define TILE_FULL(bufc, bufn2, k2) do {                                        \
    PHASE(bufc, 0, STAGE_A(bufn2, k2), (void)0);                               \
    PHASE(bufc, 1, STAGE_B(bufn2, k2), VMCNT(6));                              \
} while (0)

    // prologue: stage tiles 0 and 1
    STAGE_A(0, 0); STAGE_B(0, 0);
    STAGE_A(1, BK); STAGE_B(1, BK);
    VMCNT(6);        // tile 0 landed (tile 1's 6 still in flight)
    BARRIER();

    int k0 = 0;
#pragma unroll 1
    for (int grp = 0; grp < (NT - 2) / 3; ++grp) {   // 10 groups, tiles 0..29
        TILE_FULL(0, 2, k0 + 2 * BK);
        TILE_FULL(1, 0, k0 + 3 * BK);
        TILE_FULL(2, 1, k0 + 4 * BK);
        k0 += 3 * BK;
    }
    // tile 30 (buf0): no staging; drain tile 31's loads
    PHASE(0, 0, (void)0, (void)0);
    PHASE(0, 1, (void)0, VMCNT(0));
    // tile 31 (buf1): last
    PHASE(1, 0, (void)0, (void)0);
    PHASE(1, 1, (void)0, (void)0);

    // epilogue: C/D layout col = lane&15, row = (lane>>4)*4 + reg
#pragma unroll
    for (int m = 0; m < 4; ++m) {
        const int rbase = row0 + wr * 64 + m * 16 + fq * 4;
#pragma unroll
        for (int n = 0; n < 4; ++n) {
            const int c = col0 + wc * 64 + n * 16 + fr;
            const float tw = term_w[c];
#pragma unroll
            for (int j = 0; j < 4; ++j) {
                const int r = rbase + j;
                C[(size_t)r * COUT + c] = 0.5f * acc[m][n][j] + term_x[r] + tw;
            }
        }
    }
#undef STAGE_A
#undef STAGE_B
#undef PHASE
#undef TILE_FULL
}

// ---------------------------------------------------------------- launcher
extern "C" void kernel_launch(void* const* d_in, const int* in_sizes, int n_in,
                              void* d_out, int out_size, void* d_ws, size_t ws_size,
                              hipStream_t stream) {
    const float* x      = (const float*)d_in[0];
    const float* weight = (const float*)d_in[1];
    const float* phases = (const float*)d_in[2];
    const float* disks  = (const float*)d_in[3];
    float* out = (float*)d_out;

    char* ws = (char*)d_ws;
    float* pmax   = (float*)(ws);                    // 1 KB
    float* s_tab  = (float*)(ws + 4096);             // 8 KB
    float* dd_tab = (float*)(ws + 16384);            // 8 KB
    float* term_w = (float*)(ws + 32768);            // 8 KB
    float* term_x = (float*)(ws + 49152);            // 16 KB
    _Float16* V   = (_Float16*)(ws + 65536);                               // 8 MB
    _Float16* XQ  = (_Float16*)(ws + 65536 + (size_t)COUT * CIN * 2);      // 16 MB

    prep_a_kernel<<<B_DIM + NMAXBLK + 1, 256, 0, stream>>>(
        x, weight, phases, disks, XQ, term_x, pmax, s_tab, dd_tab);
    prep_b_kernel<<<COUT, 256, 0, stream>>>(weight, pmax, s_tab, dd_tab, V, term_w);
    gemm_kernel<<<(B_DIM / BM) * (COUT / BN), 512, 0, stream>>>(XQ, V, term_x, term_w, out);
}

// Round 5
// 62.218 us; speedup vs baseline: 1.5098x; 1.0817x over previous
//
#include <hip/hip_runtime.h>
#include <hip/hip_bf16.h>
#include <math.h>

#define B_DIM 4096
#define CIN   2048
#define COUT  2048

typedef _Float16 f16x8 __attribute__((ext_vector_type(8)));
typedef _Float16 f16x4 __attribute__((ext_vector_type(4)));
typedef float    f32x4 __attribute__((ext_vector_type(4)));

__device__ inline float wave_reduce_sum(float v) {
#pragma unroll
    for (int off = 32; off > 0; off >>= 1)
        v += __shfl_down(v, off, 64);
    return v;
}
__device__ inline float wave_reduce_max(float v) {
#pragma unroll
    for (int off = 32; off > 0; off >>= 1)
        v = fmaxf(v, __shfl_down(v, off, 64));
    return v;
}

// ---------------------------------------------------------------------------
// Kernel A (fused): blocks [0,4096)   : quantize x -> XQ (f16), term_x
//                   blocks [4096,4352): partial max|weight| -> pmax[256]
//                   block  4352       : tables s[i]=sin(phi)*(d0+d1), dd[i]=d0-d1
// ---------------------------------------------------------------------------
#define NMAXBLK 256
__global__ void prep_a_kernel(const float* __restrict__ x,
                              const float* __restrict__ weight,
                              const float* __restrict__ phases,
                              const float* __restrict__ disks,
                              _Float16* __restrict__ XQ,
                              float* __restrict__ term_x,
                              float* __restrict__ pmax,
                              float* __restrict__ s_tab,
                              float* __restrict__ dd_tab) {
    __shared__ float red[4];
    const int blk = blockIdx.x;
    const int tid = threadIdx.x;

    if (blk < B_DIM) {
        const f32x4* x4  = (const f32x4*)(x + (size_t)blk * CIN);
        const f32x4* dk  = (const f32x4*)disks;   // [CIN][2] interleaved
        f16x4* xq4 = (f16x4*)(XQ + (size_t)blk * CIN);
        float sum = 0.f;
        for (int g = tid; g < CIN / 4; g += 256) {
            f32x4 v   = x4[g];
            f32x4 dv0 = dk[2 * g];
            f32x4 dv1 = dk[2 * g + 1];
            float dd0 = dv0[0] - dv0[1], dd1 = dv0[2] - dv0[3];
            float dd2 = dv1[0] - dv1[1], dd3 = dv1[2] - dv1[3];
            f16x4 h;
            float q0 = rintf(fminf(fmaxf(v[0], 0.f), 1.f) * 255.f) * (1.f / 255.f);
            float q1 = rintf(fminf(fmaxf(v[1], 0.f), 1.f) * 255.f) * (1.f / 255.f);
            float q2 = rintf(fminf(fmaxf(v[2], 0.f), 1.f) * 255.f) * (1.f / 255.f);
            float q3 = rintf(fminf(fmaxf(v[3], 0.f), 1.f) * 255.f) * (1.f / 255.f);
            h[0] = (_Float16)q0; h[1] = (_Float16)q1;
            h[2] = (_Float16)q2; h[3] = (_Float16)q3;
            xq4[g] = h;
            sum += q0 * q0 * dd0 + q1 * q1 * dd1 + q2 * q2 * dd2 + q3 * q3 * dd3;
        }
        sum = wave_reduce_sum(sum);
        if ((tid & 63) == 0) red[tid >> 6] = sum;
        __syncthreads();
        if (tid == 0)
            term_x[blk] = 0.25f * (red[0] + red[1] + red[2] + red[3]);
    } else if (blk < B_DIM + NMAXBLK) {
        const int mb = blk - B_DIM;
        const size_t n4 = (size_t)COUT * CIN / 4;
        const f32x4* w4 = (const f32x4*)weight;
        float m = 0.f;
        for (size_t i = (size_t)mb * 256 + tid; i < n4; i += (size_t)NMAXBLK * 256) {
            f32x4 v = w4[i];
            m = fmaxf(m, fmaxf(fmaxf(fabsf(v[0]), fabsf(v[1])),
                               fmaxf(fabsf(v[2]), fabsf(v[3]))));
        }
        m = wave_reduce_max(m);
        if ((tid & 63) == 0) red[tid >> 6] = m;
        __syncthreads();
        if (tid == 0)
            pmax[mb] = fmaxf(fmaxf(red[0], red[1]), fmaxf(red[2], red[3]));
    } else {
        for (int i = tid; i < CIN; i += 256) {
            float d0 = disks[2 * i], d1 = disks[2 * i + 1];
            s_tab[i]  = sinf(phases[i]) * (d0 + d1);
            dd_tab[i] = d0 - d1;
        }
    }
}

// ---------------------------------------------------------------------------
// Kernel B: per-row weight quantize -> V = wq * s (f16), term_w
// ---------------------------------------------------------------------------
__global__ void prep_b_kernel(const float* __restrict__ weight,
                              const float* __restrict__ pmax,
                              const float* __restrict__ s_tab,
                              const float* __restrict__ dd_tab,
                              _Float16* __restrict__ V,
                              float* __restrict__ term_w) {
    __shared__ float red[4];
    __shared__ float bmax;
    const int tid = threadIdx.x;

    float m = pmax[tid];
    m = wave_reduce_max(m);
    if ((tid & 63) == 0) red[tid >> 6] = m;
    __syncthreads();
    if (tid == 0)
        bmax = tanhf(fmaxf(fmaxf(red[0], red[1]), fmaxf(red[2], red[3])));
    __syncthreads();
    const float inv2m = 0.5f / bmax;             // max|tanh(W)| = tanh(max|W|)

    const int o = blockIdx.x;
    const f32x4* w4  = (const f32x4*)(weight + (size_t)o * CIN);
    const f32x4* s4  = (const f32x4*)s_tab;
    const f32x4* dd4 = (const f32x4*)dd_tab;
    f16x4* v4 = (f16x4*)(V + (size_t)o * CIN);
    float sum = 0.f;
    for (int g = tid; g < CIN / 4; g += 256) {
        f32x4 wv = w4[g], sv = s4[g], ddv = dd4[g];
        f16x4 h;
#pragma unroll
        for (int j = 0; j < 4; ++j) {
            float t  = tanhf(wv[j]);
            float wq = rintf((t * inv2m + 0.5f) * 255.f) * (1.f / 255.f);
            sum += wq * wq * ddv[j];
            h[j] = (_Float16)(wq * sv[j]);
        }
        v4[g] = h;
    }
    sum = wave_reduce_sum(sum);
    __syncthreads();
    if ((tid & 63) == 0) red[tid >> 6] = sum;
    __syncthreads();
    if (tid == 0)
        term_w[o] = 0.25f * (red[0] + red[1] + red[2] + red[3]);
}

// ---------------------------------------------------------------------------
// Kernel C: GEMM  C[b][o] = 0.5*sum_k XQ[b][k]*V[o][k] + term_x[b] + term_w[o]
// BM=256 BN=128 BK=64, 8 waves (4Mx2N), triple-buffered LDS (144 KB, 1 blk/CU).
// ONE barrier + ONE counted vmcnt per K-tile; no intra-tile barriers. Inside a
// tile each wave free-runs {stage t+2 issue, 16 ds_read_b128, 32 MFMA} -> waves
// drift so one wave's MFMA overlaps another's LDS reads (m114 co-schedule);
// compiler interleaves slice-1 reads into slice-0 MFMA shadow (counted lgkm).
// Data safety: buffer (t+2)%3's last readers (tile t-1) retired their ds_reads
// before the t-1/t boundary barrier; vmcnt(6) at end of tile t proves tile
// t+1's 6 loads (issued at t-1, FIFO-retired) landed before the barrier
// publishes them. XOR-granule swizzle both-sides (round 3: 0 conflicts).
// ---------------------------------------------------------------------------
#define BM 256
#define BN 128
#define BK 64
#define NT (CIN / BK)        // 32
#define TILES_N (COUT / BN)  // 16

#define MEMFENCE asm volatile("" ::: "memory")
#define BARRIER() do { MEMFENCE; __builtin_amdgcn_s_barrier(); MEMFENCE; } while (0)
#define VMCNT(N) asm volatile("s_waitcnt vmcnt(" #N ")" ::: "memory")

__global__ __launch_bounds__(512, 2) void
gemm_kernel(const _Float16* __restrict__ A,   // [B_DIM][CIN]
            const _Float16* __restrict__ Bw,  // [COUT][CIN]
            const float* __restrict__ term_x, // pre*0.25
            const float* __restrict__ term_w, // pre*0.25
            float* __restrict__ C) {
    __shared__ __align__(16) _Float16 As[3][BM * BK];  // 3 x 32 KB
    __shared__ __align__(16) _Float16 Bs[3][BN * BK];  // 3 x 16 KB

    const int tid  = threadIdx.x;
    const int wave = tid >> 6;
    const int lane = tid & 63;

    const int tile_m = blockIdx.x / TILES_N;
    const int tile_n = blockIdx.x % TILES_N;
    const int row0 = tile_m * BM;
    const int col0 = tile_n * BN;
    const int wr = wave >> 1;   // 0..3 (M)
    const int wc = wave & 1;    // 0..1 (N)

    f32x4 acc[4][4];
#pragma unroll
    for (int m = 0; m < 4; ++m)
#pragma unroll
        for (int n = 0; n < 4; ++n)
            acc[m][n] = (f32x4){0.f, 0.f, 0.f, 0.f};

    // staging: chunk = 8 rows x 64 f16 = 1 KB = one global_load_lds per wave.
    // lane l -> row l>>3, phys granule l&7; source fetches logical granule
    // (l&7)^(row&7)  (involution with the read swizzle).
    const int st_row = lane >> 3;
    const int st_col = ((lane & 7) ^ (st_row & 7)) * 8;
    const _Float16* Agp = A  + (size_t)row0 * CIN;
    const _Float16* Bgp = Bw + (size_t)col0 * CIN;

    const int fr = lane & 15;
    const int fq = lane >> 4;      // 0..3
    const int hh = fr & 7;

    // loop-invariant LDS read offsets (elements): logical granule ks*4+fq of
    // row r lives at physical granule (ks*4+fq)^(r&7).
    int offA[2][4], offB[2][4];
#pragma unroll
    for (int s = 0; s < 2; ++s)
#pragma unroll
        for (int m = 0; m < 4; ++m) {
            offA[s][m] = (wr * 64 + m * 16 + fr) * BK + (((s * 4 + fq) ^ hh) * 8);
            offB[s][m] = (wc * 64 + m * 16 + fr) * BK + (((s * 4 + fq) ^ hh) * 8);
        }

#define STAGE_A(buf, k0) do {                                                  \
    _Pragma("unroll")                                                          \
    for (int j = 0; j < 4; ++j) {                                              \
        const int chunk = wave + j * 8;     /* 32 chunks cover 256 rows */     \
        const int rr = chunk * 8 + st_row;                                     \
        __builtin_amdgcn_global_load_lds(                                      \
            (const __attribute__((address_space(1))) void*)(Agp + (size_t)rr * CIN + (k0) + st_col), \
            (__attribute__((address_space(3))) void*)(&As[buf][chunk * 512]),  \
            16, 0, 0);                                                         \
    } } while (0)

#define STAGE_B(buf, k0) do {                                                  \
    _Pragma("unroll")                                                          \
    for (int j = 0; j < 2; ++j) {                                              \
        const int chunk = wave + j * 8;     /* 16 chunks cover 128 rows */     \
        const int rr = chunk * 8 + st_row;                                     \
        __builtin_amdgcn_global_load_lds(                                      \
            (const __attribute__((address_space(1))) void*)(Bgp + (size_t)rr * CIN + (k0) + st_col), \
            (__attribute__((address_space(3))) void*)(&Bs[buf][chunk * 512]),  \
            16, 0, 0);                                                         \
    } } while (0)

// One K-tile: stage t+2 (issue-early), 2 k-slices of {8 ds_read_b128 +
// 16 MFMA w/ setprio}, counted vmcnt, ONE barrier.
#define TILE(bufc, DO_STAGE, bufn2, k2, VM_STMT) do {                          \
    if (DO_STAGE) { STAGE_A(bufn2, k2); STAGE_B(bufn2, k2); }                  \
    _Pragma("unroll")                                                          \
    for (int s = 0; s < 2; ++s) {                                              \
        f16x8 af[4], bf[4];                                                    \
        _Pragma("unroll")                                                      \
        for (int m = 0; m < 4; ++m)                                            \
            af[m] = *(const f16x8*)(&As[bufc][offA[s][m]]);                    \
        _Pragma("unroll")                                                      \
        for (int n = 0; n < 4; ++n)                                            \
            bf[n] = *(const f16x8*)(&Bs[bufc][offB[s][n]]);                    \
        __builtin_amdgcn_s_setprio(1);                                         \
        _Pragma("unroll")                                                      \
        for (int m = 0; m < 4; ++m)                                            \
            _Pragma("unroll")                                                  \
            for (int n = 0; n < 4; ++n)                                        \
                acc[m][n] = __builtin_amdgcn_mfma_f32_16x16x32_f16(            \
                    af[m], bf[n], acc[m][n], 0, 0, 0);                         \
        __builtin_amdgcn_s_setprio(0);                                         \
    }                                                                          \
    VM_STMT;                                                                   \
    BARRIER();                                                                 \
} while (0)

    // prologue: stage tiles 0 and 1 (6 loads each)
    STAGE_A(0, 0); STAGE_B(0, 0);
    STAGE_A(1, BK); STAGE_B(1, BK);
    VMCNT(6);        // tile 0 landed (tile 1's 6 still in flight)
    BARRIER();

    int k0 = 0;
#pragma unroll 1
    for (int grp = 0; grp < (NT - 2) / 3; ++grp) {   // 10 groups, tiles 0..29
        TILE(0, true, 2, k0 + 2 * BK, VMCNT(6));
        TILE(1, true, 0, k0 + 3 * BK, VMCNT(6));
        TILE(2, true, 1, k0 + 4 * BK, VMCNT(6));
        k0 += 3 * BK;
    }
    // tile 30 (buf0): no staging; drain tile 31's loads
    TILE(0, false, 0, 0, VMCNT(0));
    // tile 31 (buf1): last
    TILE(1, false, 0, 0, (void)0);

    // epilogue: C/D layout col = lane&15, row = (lane>>4)*4 + reg
#pragma unroll
    for (int m = 0; m < 4; ++m) {
        const int rbase = row0 + wr * 64 + m * 16 + fq * 4;
#pragma unroll
        for (int n = 0; n < 4; ++n) {
            const int c = col0 + wc * 64 + n * 16 + fr;
            const float tw = term_w[c];
#pragma unroll
            for (int j = 0; j < 4; ++j) {
                const int r = rbase + j;
                C[(size_t)r * COUT + c] = 0.5f * acc[m][n][j] + term_x[r] + tw;
            }
        }
    }
#undef STAGE_A
#undef STAGE_B
#undef TILE
}

// ---------------------------------------------------------------- launcher
extern "C" void kernel_launch(void* const* d_in, const int* in_sizes, int n_in,
                              void* d_out, int out_size, void* d_ws, size_t ws_size,
                              hipStream_t stream) {
    const float* x      = (const float*)d_in[0];
    const float* weight = (const float*)d_in[1];
    const float* phases = (const float*)d_in[2];
    const float* disks  = (const float*)d_in[3];
    float* out = (float*)d_out;

    char* ws = (char*)d_ws;
    float* pmax   = (float*)(ws);                    // 1 KB
    float* s_tab  = (float*)(ws + 4096);             // 8 KB
    float* dd_tab = (float*)(ws + 16384);            // 8 KB
    float* term_w = (float*)(ws + 32768);            // 8 KB
    float* term_x = (float*)(ws + 49152);            // 16 KB
    _Float16* V   = (_Float16*)(ws + 65536);                               // 8 MB
    _Float16* XQ  = (_Float16*)(ws + 65536 + (size_t)COUT * CIN * 2);      // 16 MB

    prep_a_kernel<<<B_DIM + NMAXBLK + 1, 256, 0, stream>>>(
        x, weight, phases, disks, XQ, term_x, pmax, s_tab, dd_tab);
    prep_b_kernel<<<COUT, 256, 0, stream>>>(weight, pmax, s_tab, dd_tab, V, term_w);
    gemm_kernel<<<(B_DIM / BM) * (COUT / BN), 512, 0, stream>>>(XQ, V, term_x, term_w, out);
}